// Round 3
// baseline (544.095 us; speedup 1.0000x reference)
//
#include <hip/hip_runtime.h>
#include <hip/hip_bf16.h>
#include <stdint.h>

#define N_NODES 100000
#define DEG 16
#define D_IN 128
#define D_OUT 256
#define K_TOP 32
#define K_CAT 256   // concatenated K = D_IN(self) + D_IN(neigh)

typedef __attribute__((ext_vector_type(8))) short short8;
typedef __attribute__((ext_vector_type(4))) float floatx4;

__device__ __forceinline__ unsigned pack_bf16_rne(float f) {
    union { float f; unsigned u; } c; c.f = f;
    unsigned u = c.u;
    return (u + 0x7fffu + ((u >> 16) & 1u)) >> 16;   // round-to-nearest-even
}
__device__ __forceinline__ float bf16lo_to_f(unsigned lo16) {
    union { unsigned u; float f; } c; c.u = lo16 << 16; return c.f;
}

// async global->LDS, 16B per lane; LDS dest is wave-uniform base + lane*16
typedef __attribute__((address_space(1))) void as1_void;
typedef __attribute__((address_space(3))) void as3_void;
__device__ __forceinline__ void gload_lds16(const void* g, void* l) {
    __builtin_amdgcn_global_load_lds((as1_void*)g, (as3_void*)l, 16, 0, 0);
}

// ---------------- kernel 1 (merged prep): feat->bf16 | topk pack | weight pack ---------
// Packed top-k record per node: 96 B = bf16 vals[32] (64B) + u8 idx[32] (32B).
#define FEAT_BLKS 1563   // ceil(N/64)
#define PACK_BLKS 1563

__global__ __launch_bounds__(256) void k_prep(const float* __restrict__ feat,
                                              const float* __restrict__ topk_v,
                                              const int* __restrict__ topk_i,
                                              const float* __restrict__ w_self,
                                              const float* __restrict__ w_neigh,
                                              unsigned short* __restrict__ fbf,
                                              unsigned char* __restrict__ pkrec,
                                              unsigned short* __restrict__ bmat) {
    const int t = threadIdx.x;
    const int bid = blockIdx.x;
    if (bid < FEAT_BLKS) {
        // feat f32 -> fbf bf16, 64 rows/block, stride 128
        const int row0 = bid * 64;
        #pragma unroll
        for (int p = 0; p < 8; ++p) {
            int q = t + p * 256;             // 0..2047
            int r = q >> 5;                  // 0..63
            int c4 = (q & 31) * 4;
            if (row0 + r < N_NODES) {
                float4 f = *(const float4*)(feat + (size_t)(row0 + r) * D_IN + c4);
                uint2 pv;
                pv.x = pack_bf16_rne(f.x) | (pack_bf16_rne(f.y) << 16);
                pv.y = pack_bf16_rne(f.z) | (pack_bf16_rne(f.w) << 16);
                ((uint2*)(fbf + (size_t)(row0 + r) * D_IN))[q & 31] = pv;
            }
        }
    } else if (bid < FEAT_BLKS + PACK_BLKS) {
        // pack topk: 64 nodes/block, 4 threads/node, 8 (val,idx) pairs each
        const int n = (bid - FEAT_BLKS) * 64 + (t >> 2);
        const int p = t & 3;
        if (n < N_NODES) {
            const float* vs = topk_v + (size_t)n * K_TOP + p * 8;
            float4 v0 = ((const float4*)vs)[0];
            float4 v1 = ((const float4*)vs)[1];
            const int* is = topk_i + (size_t)n * K_TOP + p * 8;
            int4 i0 = ((const int4*)is)[0];
            int4 i1 = ((const int4*)is)[1];
            uint4 pv;
            pv.x = pack_bf16_rne(v0.x) | (pack_bf16_rne(v0.y) << 16);
            pv.y = pack_bf16_rne(v0.z) | (pack_bf16_rne(v0.w) << 16);
            pv.z = pack_bf16_rne(v1.x) | (pack_bf16_rne(v1.y) << 16);
            pv.w = pack_bf16_rne(v1.z) | (pack_bf16_rne(v1.w) << 16);
            uint2 pi;
            pi.x = (unsigned)i0.x | ((unsigned)i0.y << 8) | ((unsigned)i0.z << 16) | ((unsigned)i0.w << 24);
            pi.y = (unsigned)i1.x | ((unsigned)i1.y << 8) | ((unsigned)i1.z << 16) | ((unsigned)i1.w << 24);
            unsigned char* rec = pkrec + (size_t)n * 96;
            *(uint4*)(rec + p * 16) = pv;
            *(uint2*)(rec + 64 + p * 8) = pi;
        }
    } else {
        // pack [w_self | w_neigh] -> bf16 B[256][256]
        const int o = bid - (FEAT_BLKS + PACK_BLKS);   // 0..255
        const int k = t;
        float v = (k < D_IN) ? w_self[o * D_IN + k] : w_neigh[o * D_IN + (k - D_IN)];
        bmat[o * K_CAT + k] = (unsigned short)pack_bf16_rne(v);
    }
}

// ------ kernel 2 (fused): sparse scatter-aggregate in LDS, then GEMM over K=256 --------
// out[N][256] = [fbf | agg] @ B[256][256]^T + bias.
// Phase 1: for each edge, gather the 96B packed record of its source node and
// ds_add_f32-scatter w*val into a 64-row f32 LDS accumulator (2 passes of 64 rows),
// packing each pass to a persistent XOR-swizzled bf16 tile.
// Phase 2: round-2 GEMM loop: BM=128, BN=256, BK=32, 8 waves (2x4), swapped-operand
// mfma_f32_16x16x32_bf16; A = staged fbf (kt 0-3) then LDS aggbf (kt 4-7).
// LDS aliasing: aggf32 (32K) overlaps As[0..1]+Bs[0] (dead until GEMM); Bs[1] free ->
// kt=0 B-tile prefetch issues at kernel start.
#define BM 128
#define BN 256
#define BK 32
#define NTA 4
#define NT  8

__global__ __launch_bounds__(512, 4) void k_fused(const float* __restrict__ csr_w,
                                                  const int* __restrict__ col_idx,
                                                  const unsigned char* __restrict__ pkrec,
                                                  const unsigned short* __restrict__ fbf,
                                                  const unsigned short* __restrict__ bmat,
                                                  const float* __restrict__ bias,
                                                  float* __restrict__ out) {
    __shared__ __align__(16) char smem[81920];                               // 80 KiB
    unsigned short* aggbf = (unsigned short*)smem;                           // [128][128] swizzled, 32K
    float* aggf = (float*)(smem + 32768);                                    // [64][128] f32, 32K (aliased)
    unsigned short (*As)[BM * BK] = (unsigned short (*)[BM * BK])(smem + 32768);   // 2 x 8K
    unsigned short (*Bs)[BN * BK] = (unsigned short (*)[BN * BK])(smem + 49152);   // 2 x 16K

    const int t = threadIdx.x;
    const int lane = t & 63, wave = t >> 6;
    const int l16 = lane & 15, quad = lane >> 4;
    const int row0 = blockIdx.x * BM;

    // staging geometry (round-2): wave covers 16 rows x 4x16B chunks, linear LDS
    const int a_r = wave * 16 + (lane >> 2);
    const int a_c = (lane & 3) * 8;                          // shorts
    int a_gr = row0 + a_r; if (a_gr >= N_NODES) a_gr = N_NODES - 1;   // clamp: never stored
    const unsigned short* gA  = fbf  + (size_t)a_gr * D_IN + a_c;
    const unsigned short* gB0 = bmat + (size_t)a_r        * K_CAT + a_c;
    const unsigned short* gB1 = bmat + (size_t)(a_r + 128) * K_CAT + a_c;

#define STAGE_A(buf, tt) gload_lds16(gA + (tt) * BK, &As[buf][wave * 16 * BK])
#define STAGE_B(buf, tt) do {                                                 \
        gload_lds16(gB0 + (tt) * BK, &Bs[buf][(wave * 16)       * BK]);       \
        gload_lds16(gB1 + (tt) * BK, &Bs[buf][(wave * 16 + 128) * BK]);       \
    } while (0)

    STAGE_B(1, 0);   // Bs[1] does not alias aggf32 -> safe to fly during phase 1

    // zero aggf32: 8192 floats / 512 thr = 4 float4 each
    #pragma unroll
    for (int p = 0; p < 4; ++p)
        *(floatx4*)&aggf[(t + p * 512) * 4] = (floatx4){0.f, 0.f, 0.f, 0.f};
    __syncthreads();

    // ---- phase 1: two 64-row scatter+pack passes ----
    #pragma unroll 1
    for (int pass = 0; pass < 2; ++pass) {
        const int rbase = row0 + pass * 64;
        const int ebase = rbase * DEG;
        // scatter: 1024 edges x 4 record-parts = 4096 slots, 8/thread
        #pragma unroll 4
        for (int s = 0; s < 8; ++s) {
            int q = s * 512 + t;             // 0..4095
            int e = q >> 2;                  // local edge 0..1023
            int p = q & 3;                   // record part
            int lr = e >> 4;                 // local row 0..63
            if (rbase + lr < N_NODES) {
                int   col = col_idx[ebase + e];      // 4 lanes share -> broadcast
                float w   = csr_w [ebase + e];
                const unsigned char* rec = pkrec + (size_t)col * 96;
                uint4 v  = *(const uint4*)(rec + p * 16);       // 8 bf16 vals
                uint2 id = *(const uint2*)(rec + 64 + p * 8);   // 8 u8 idx
                float* arow = aggf + lr * D_IN;
                atomicAdd(&arow[ id.x        & 255], w * bf16lo_to_f(v.x & 0xffffu));
                atomicAdd(&arow[(id.x >>  8) & 255], w * bf16lo_to_f(v.x >> 16));
                atomicAdd(&arow[(id.x >> 16) & 255], w * bf16lo_to_f(v.y & 0xffffu));
                atomicAdd(&arow[ id.x >> 24       ], w * bf16lo_to_f(v.y >> 16));
                atomicAdd(&arow[ id.y        & 255], w * bf16lo_to_f(v.z & 0xffffu));
                atomicAdd(&arow[(id.y >>  8) & 255], w * bf16lo_to_f(v.z >> 16));
                atomicAdd(&arow[(id.y >> 16) & 255], w * bf16lo_to_f(v.w & 0xffffu));
                atomicAdd(&arow[ id.y >> 24       ], w * bf16lo_to_f(v.w >> 16));
            }
        }
        __syncthreads();
        // pack aggf -> aggbf rows [pass*64, pass*64+64), XOR-swizzled; re-zero for pass 0
        #pragma unroll
        for (int s = 0; s < 8; ++s) {
            int d  = s * 512 + t;            // dword 0..4095
            int lr = d >> 6;                 // 0..63
            int c2 = (d & 63) * 2;           // even short/float col
            float2 v = *(const float2*)&aggf[lr * D_IN + c2];
            int R = pass * 64 + lr;
            *(unsigned*)&aggbf[R * D_IN + (c2 ^ ((R & 7) << 3))] =
                pack_bf16_rne(v.x) | (pack_bf16_rne(v.y) << 16);
            if (pass == 0) *(float2*)&aggf[lr * D_IN + c2] = make_float2(0.f, 0.f);
        }
        __syncthreads();
    }

    // aggf32 dead from here; As/Bs[0] regions now usable
    STAGE_A(0, 0);

    floatx4 acc[4][4];
    #pragma unroll
    for (int i = 0; i < 4; ++i)
        #pragma unroll
        for (int j = 0; j < 4; ++j)
            acc[i][j] = (floatx4){0.f, 0.f, 0.f, 0.f};

    __syncthreads();   // drains vmcnt: As[0]/Bs[1] staged, aggbf visible

    // ---- phase 2: GEMM K-loop (B read buffer = (tt+1)&1 so kt0 uses early Bs[1]) ----
    const int wr = wave >> 2, wc = wave & 3;                 // 2x4 wave grid, 64x64 each
    #pragma unroll
    for (int tt = 0; tt < NT; ++tt) {
        const int cur = tt & 1;
        if (tt + 1 < NTA) STAGE_A(cur ^ 1, tt + 1);          // prefetch next A (fbf half)
        if (tt + 1 < NT)  STAGE_B(cur, tt + 1);              // prefetch next B (into read^1)

        short8 afr[4], bfr[4];
        if (tt < NTA) {
            #pragma unroll
            for (int i = 0; i < 4; ++i)
                afr[i] = *(const short8*)&As[cur][(wr * 64 + i * 16 + l16) * BK + quad * 8];
        } else {
            const int c0 = (tt - NTA) * 32 + quad * 8;
            #pragma unroll
            for (int i = 0; i < 4; ++i) {
                const int m = wr * 64 + i * 16 + l16;
                afr[i] = *(const short8*)&aggbf[m * 128 + (c0 ^ ((m & 7) << 3))];
            }
        }
        #pragma unroll
        for (int j = 0; j < 4; ++j)
            bfr[j] = *(const short8*)&Bs[cur ^ 1][(wc * 64 + j * 16 + l16) * BK + quad * 8];

        #pragma unroll
        for (int i = 0; i < 4; ++i)
            #pragma unroll
            for (int j = 0; j < 4; ++j)   // swapped: out-rows <- afr lanes, out-cols <- bfr regs
                acc[i][j] = __builtin_amdgcn_mfma_f32_16x16x32_bf16(bfr[j], afr[i], acc[i][j], 0, 0, 0);

        if (tt + 1 < NT) __syncthreads();
    }

    // epilogue: lane holds row m = l16 (+16i+64wr), cols quad*4..+3 (+16j+64wc) -> float4
    #pragma unroll
    for (int j = 0; j < 4; ++j) {
        const int cg = wc * 64 + j * 16 + quad * 4;
        const float4 bv = *(const float4*)&bias[cg];
        #pragma unroll
        for (int i = 0; i < 4; ++i) {
            const int gr = row0 + wr * 64 + i * 16 + l16;
            if (gr < N_NODES) {
                float4 v;
                v.x = acc[i][j][0] + bv.x;
                v.y = acc[i][j][1] + bv.y;
                v.z = acc[i][j][2] + bv.z;
                v.w = acc[i][j][3] + bv.w;
                *(float4*)(out + (size_t)gr * D_OUT + cg) = v;
            }
        }
    }
#undef STAGE_A
#undef STAGE_B
}

extern "C" void kernel_launch(void* const* d_in, const int* in_sizes, int n_in,
                              void* d_out, int out_size, void* d_ws, size_t ws_size,
                              hipStream_t stream) {
    const float* feat    = (const float*)d_in[0];
    const float* topk_v  = (const float*)d_in[1];
    const float* csr_w   = (const float*)d_in[2];
    const float* w_neigh = (const float*)d_in[3];
    const float* w_self  = (const float*)d_in[4];
    const float* b_self  = (const float*)d_in[5];
    const int*   topk_i  = (const int*)d_in[6];
    // d_in[7] = indptr (fixed degree 16, unused), d_in[8] = indices
    const int*   indices = (const int*)d_in[8];
    float* out = (float*)d_out;

    // workspace layout: fbf bf16[N*128] (25.6MB) | pkrec u8[N*96] (9.6MB) | bmat bf16[256*256]
    unsigned char* base = (unsigned char*)d_ws;
    unsigned short* fbf   = (unsigned short*)base;
    unsigned char*  pkrec = base + (size_t)N_NODES * D_IN * 2;
    unsigned short* bmat  = (unsigned short*)(pkrec + (size_t)N_NODES * 96);

    k_prep<<<dim3(FEAT_BLKS + PACK_BLKS + 256), dim3(256), 0, stream>>>(
        feat, topk_v, topk_i, w_self, w_neigh, fbf, pkrec, bmat);
    k_fused<<<dim3((N_NODES + BM - 1) / BM), dim3(512), 0, stream>>>(
        csr_w, indices, pkrec, fbf, bmat, b_self, out);
}